// Round 1
// baseline (1044.197 us; speedup 1.0000x reference)
//
#include <hip/hip_runtime.h>
#include <stdint.h>

#define N_NODES 10000
#define N_EDGES 160000
#define N_REL   4
#define N_GRAPHS 256
#define NBUCKET (N_NODES * N_REL)   // 40000 (dst,rel) buckets

typedef __attribute__((ext_vector_type(8))) short short8;
typedef __attribute__((ext_vector_type(4))) float float4v;

// ---------- helpers ----------
__device__ __forceinline__ unsigned short f2bf(float f) {
  unsigned int u = __float_as_uint(f);
  u = u + 0x7FFFu + ((u >> 16) & 1u);   // round-to-nearest-even
  return (unsigned short)(u >> 16);
}

__device__ __forceinline__ void g2lds16(const void* g, void* l) {
  // async global->LDS, 16B per lane; LDS dest = wave-uniform base + lane*16
  __builtin_amdgcn_global_load_lds(
      (const __attribute__((address_space(1))) void*)g,
      (__attribute__((address_space(3))) void*)l, 16, 0, 0);
}

__device__ __forceinline__ int lower_bound_i(const int* a, int n, int key) {
  int lo = 0, hi = n;
  while (lo < hi) { int mid = (lo + hi) >> 1; if (a[mid] < key) lo = mid + 1; else hi = mid; }
  return lo;
}

// ---------- CSR build ----------
__global__ void count_edges_k(const int* __restrict__ ei, const int* __restrict__ et,
                              int* __restrict__ cnt, int E) {
  int e = blockIdx.x * 256 + threadIdx.x;
  if (e < E) atomicAdd(&cnt[ei[E + e] * N_REL + et[e]], 1);
}

__global__ void scan_block_k(const int* __restrict__ cnt, int* __restrict__ eexcl,
                             int* __restrict__ btot, int n) {
  int i = blockIdx.x * 256 + threadIdx.x;
  int v = (i < n) ? cnt[i] : 0;
  int lane = threadIdx.x & 63, wv = threadIdx.x >> 6;
  int s = v;
  #pragma unroll
  for (int off = 1; off < 64; off <<= 1) {
    int t = __shfl_up(s, off, 64);
    if (lane >= off) s += t;
  }
  __shared__ int wt[4];
  if (lane == 63) wt[wv] = s;
  __syncthreads();
  int wadd = 0;
  for (int w = 0; w < wv; ++w) wadd += wt[w];
  int incl = s + wadd;
  if (i < n) eexcl[i] = incl - v;
  if (threadIdx.x == 255) btot[blockIdx.x] = incl;
}

__global__ void scan_final_k(const int* __restrict__ cnt, const int* __restrict__ eexcl,
                             const int* __restrict__ btot, int* __restrict__ offs,
                             int* __restrict__ cursor, float* __restrict__ inv, int n) {
  __shared__ int wred[4];
  __shared__ int sboff;
  int t = threadIdx.x;
  int part = (t < (int)blockIdx.x) ? btot[t] : 0;   // gridDim <= 256
  #pragma unroll
  for (int off = 32; off > 0; off >>= 1) part += __shfl_down(part, off, 64);
  if ((t & 63) == 0) wred[t >> 6] = part;
  __syncthreads();
  if (t == 0) sboff = wred[0] + wred[1] + wred[2] + wred[3];
  __syncthreads();
  int i = blockIdx.x * 256 + t;
  if (i < n) {
    int o = sboff + eexcl[i];
    offs[i] = o;
    cursor[i] = o;
    int c = cnt[i];
    inv[i] = 1.0f / (float)(c > 1 ? c : 1);
  }
}

__global__ void fill_csr_k(const int* __restrict__ ei, const int* __restrict__ et,
                           int* __restrict__ cursor, int* __restrict__ elist, int E) {
  int e = blockIdx.x * 256 + threadIdx.x;
  if (e >= E) return;
  int dst = ei[E + e], src = ei[e], r = et[e];
  int pos = atomicAdd(&cursor[dst * N_REL + r], 1);
  elist[pos] = src;
}

// ---------- Wcat build: [F][K] bf16, K = 5*Din, rows 0..4Din-1 from W, rest from root ----------
__global__ void wcat_transpose_k(const float* __restrict__ W, const float* __restrict__ root,
                                 unsigned short* __restrict__ out, int Din4, int F, int K) {
  __shared__ float tile[32][33];
  int kb = blockIdx.x * 32, fb = blockIdx.y * 32;
  for (int i = threadIdx.y; i < 32; i += 8) {
    int k = kb + i, f = fb + threadIdx.x;
    float v = 0.0f;
    if (k < K && f < F) v = (k < Din4) ? W[(size_t)k * F + f] : root[(size_t)(k - Din4) * F + f];
    tile[i][threadIdx.x] = v;
  }
  __syncthreads();
  for (int i = threadIdx.y; i < 32; i += 8) {
    int f = fb + i, k = kb + threadIdx.x;
    if (f < F && k < K) out[(size_t)f * K + k] = f2bf(tile[threadIdx.x][i]);
  }
}

// ---------- aggregation: Xcat[n] = [mean_r0 | mean_r1 | mean_r2 | mean_r3 | x[n]] in bf16 ----------
__global__ void aggregate_k(const float* __restrict__ x, const int* __restrict__ offs,
                            const int* __restrict__ cnt, const float* __restrict__ inv,
                            const int* __restrict__ elist, unsigned short* __restrict__ Xcat,
                            int Din, int K5) {
  int n = blockIdx.x;
  int tid = threadIdx.x;
  int c4 = Din >> 2;                       // float4 columns
  __shared__ int sid[256];
  for (int r = 0; r < N_REL; ++r) {
    int b = n * N_REL + r;
    int start = offs[b], c = cnt[b];
    float sc = inv[b];
    float4 acc = make_float4(0.f, 0.f, 0.f, 0.f);
    for (int base = 0; base < c; base += 256) {
      int m = min(256, c - base);
      __syncthreads();
      if (tid < m) sid[tid] = elist[start + base + tid];
      __syncthreads();
      if (tid < c4) {
        for (int j = 0; j < m; ++j) {
          float4 v = *((const float4*)(x + (size_t)sid[j] * Din) + tid);
          acc.x += v.x; acc.y += v.y; acc.z += v.z; acc.w += v.w;
        }
      }
    }
    if (tid < c4) {
      ushort4 o;
      o.x = f2bf(acc.x * sc); o.y = f2bf(acc.y * sc);
      o.z = f2bf(acc.z * sc); o.w = f2bf(acc.w * sc);
      *(ushort4*)&Xcat[(size_t)n * K5 + r * Din + tid * 4] = o;
    }
  }
  if (tid < c4) {  // root block: x itself
    float4 v = *((const float4*)(x + (size_t)n * Din) + tid);
    ushort4 o;
    o.x = f2bf(v.x); o.y = f2bf(v.y); o.z = f2bf(v.z); o.w = f2bf(v.w);
    *(ushort4*)&Xcat[(size_t)n * K5 + 4 * Din + tid * 4] = o;
  }
}

// ---------- GEMM: C[M,F] = relu(A[M,K](bf16) @ Bt[F,K]^T(bf16) + bias), m97 structure ----------
__global__ __launch_bounds__(256) void gemm_bt_bias_relu_k(
    const short* __restrict__ A, const short* __restrict__ Bt,
    const float* __restrict__ bias, float* __restrict__ C,
    int M, int Ndim, int K) {
  __shared__ short As[128 * 32];
  __shared__ short Bs[128 * 32];

  const int tid = threadIdx.x;
  const int wave = tid >> 6;
  const int lane = tid & 63;
  const int mBase = blockIdx.y * 128;
  const int nBase = blockIdx.x * 128;
  const int half = lane >> 4;     // k-quad 0..3
  const int lrow = lane & 15;
  const int wm = (wave >> 1) * 64;
  const int wn = (wave & 1) * 64;
  const int srow = lane >> 2;     // staging: row within wave's 16-row group
  const int schunk = lane & 3;    // staging: 16B chunk within 64B row

  float4v acc[4][4] = {};

  for (int k0 = 0; k0 < K; k0 += 32) {
    #pragma unroll
    for (int p = 0; p < 2; ++p) {
      int r = p * 64 + wave * 16 + srow;
      int gr = mBase + r; if (gr > M - 1) gr = M - 1;
      g2lds16(A + (size_t)gr * K + k0 + schunk * 8, &As[(p * 64 + wave * 16) * 32]);
      int gn = nBase + r; if (gn > Ndim - 1) gn = Ndim - 1;
      g2lds16(Bt + (size_t)gn * K + k0 + schunk * 8, &Bs[(p * 64 + wave * 16) * 32]);
    }
    __syncthreads();

    short8 a[4], b[4];
    #pragma unroll
    for (int i = 0; i < 4; ++i)
      a[i] = *(const short8*)&As[(wm + i * 16 + lrow) * 32 + half * 8];
    #pragma unroll
    for (int j = 0; j < 4; ++j)
      b[j] = *(const short8*)&Bs[(wn + j * 16 + lrow) * 32 + half * 8];
    #pragma unroll
    for (int i = 0; i < 4; ++i)
      #pragma unroll
      for (int j = 0; j < 4; ++j)
        acc[i][j] = __builtin_amdgcn_mfma_f32_16x16x32_bf16(a[i], b[j], acc[i][j], 0, 0, 0);
    __syncthreads();
  }

  #pragma unroll
  for (int i = 0; i < 4; ++i) {
    int row0 = mBase + wm + i * 16 + half * 4;
    #pragma unroll
    for (int j = 0; j < 4; ++j) {
      int col = nBase + wn + j * 16 + lrow;
      if (col < Ndim) {
        float bv = bias[col];
        #pragma unroll
        for (int r = 0; r < 4; ++r) {
          int rr = row0 + r;
          if (rr < M) C[(size_t)rr * Ndim + col] = fmaxf(acc[i][j][r] + bv, 0.0f);
        }
      }
    }
  }
}

// ---------- pooling: per-graph mean over sorted batch ----------
__global__ void pool_k(const float* __restrict__ h, const int* __restrict__ batch,
                       float* __restrict__ g, int N, int F) {
  int gid = blockIdx.x;
  int lo = lower_bound_i(batch, N, gid);
  int hi = lower_bound_i(batch, N, gid + 1);
  float scale = (hi > lo) ? 1.0f / (float)(hi - lo) : 0.0f;
  for (int col = threadIdx.x; col < F; col += blockDim.x) {
    float s = 0.0f;
    for (int n = lo; n < hi; ++n) s += h[(size_t)n * F + col];
    g[(size_t)gid * F + col] = s * scale;
  }
}

// ---------- head MLP: out[g] = relu(g@fw1+fb1) @ fw2 + fb2 ----------
__global__ void mlp_k(const float* __restrict__ g, const float* __restrict__ fw1,
                      const float* __restrict__ fb1, const float* __restrict__ fw2,
                      const float* __restrict__ fb2, float* __restrict__ out, int F) {
  int gid = blockIdx.x;
  int t = threadIdx.x;  // 64 threads = 1 wave
  float a = fb1[t];
  for (int d = 0; d < F; ++d) a += g[(size_t)gid * F + d] * fw1[d * 64 + t];
  a = fmaxf(a, 0.0f);
  float p = a * fw2[t];
  #pragma unroll
  for (int off = 32; off > 0; off >>= 1) p += __shfl_down(p, off, 64);
  if (t == 0) out[gid] = p + fb2[0];
}

// ---------- launch ----------
extern "C" void kernel_launch(void* const* d_in, const int* in_sizes, int n_in,
                              void* d_out, int out_size, void* d_ws, size_t ws_size,
                              hipStream_t stream) {
  (void)in_sizes; (void)n_in; (void)out_size;
  const float* x    = (const float*)d_in[0];
  const int*  ei    = (const int*)d_in[1];
  const int*  et    = (const int*)d_in[2];
  const int*  batch = (const int*)d_in[3];
  const float* W1 = (const float*)d_in[4],  *root1 = (const float*)d_in[5],  *b1 = (const float*)d_in[6];
  const float* W2 = (const float*)d_in[7],  *root2 = (const float*)d_in[8],  *b2 = (const float*)d_in[9];
  const float* W3 = (const float*)d_in[10], *root3 = (const float*)d_in[11], *b3 = (const float*)d_in[12];
  const float* fw1 = (const float*)d_in[13], *fb1 = (const float*)d_in[14];
  const float* fw2 = (const float*)d_in[15], *fb2 = (const float*)d_in[16];
  float* out = (float*)d_out;

  // workspace layout (~197 MB)
  char* ws = (char*)d_ws;
  size_t off = 0;
  auto alloc = [&](size_t bytes) -> void* {
    void* p = ws + off; off += (bytes + 255) & ~(size_t)255; return p;
  };
  int*   cnt    = (int*)alloc(NBUCKET * 4);
  int*   offs   = (int*)alloc(NBUCKET * 4);
  int*   cursor = (int*)alloc(NBUCKET * 4);
  int*   eexcl  = (int*)alloc(NBUCKET * 4);
  int*   btot   = (int*)alloc(256 * 4);
  int*   elist  = (int*)alloc(N_EDGES * 4);
  float* inv    = (float*)alloc(NBUCKET * 4);
  unsigned short* Xcat  = (unsigned short*)alloc((size_t)N_NODES * 5120 * 2);
  unsigned short* WcatT = (unsigned short*)alloc((size_t)1024 * 5120 * 2);
  float* hA = (float*)alloc((size_t)N_NODES * 1024 * 4);
  float* hB = (float*)alloc((size_t)N_NODES * 1024 * 4);
  float* g  = (float*)alloc((size_t)N_GRAPHS * 712 * 4);
  (void)ws_size;  // needs ~197 MB

  // CSR by (dst, rel)
  hipMemsetAsync(cnt, 0, NBUCKET * 4, stream);
  count_edges_k<<<(N_EDGES + 255) / 256, 256, 0, stream>>>(ei, et, cnt, N_EDGES);
  int nsb = (NBUCKET + 255) / 256;  // 157 blocks (<256)
  scan_block_k<<<nsb, 256, 0, stream>>>(cnt, eexcl, btot, NBUCKET);
  scan_final_k<<<nsb, 256, 0, stream>>>(cnt, eexcl, btot, offs, cursor, inv, NBUCKET);
  fill_csr_k<<<(N_EDGES + 255) / 256, 256, 0, stream>>>(ei, et, cursor, elist, N_EDGES);

  // layer 1: Din=64, K=320, F=1024, x -> hA
  wcat_transpose_k<<<dim3(10, 32), dim3(32, 8), 0, stream>>>(W1, root1, WcatT, 256, 1024, 320);
  aggregate_k<<<N_NODES, 256, 0, stream>>>(x, offs, cnt, inv, elist, Xcat, 64, 320);
  gemm_bt_bias_relu_k<<<dim3(8, 79), 256, 0, stream>>>(
      (const short*)Xcat, (const short*)WcatT, b1, hA, N_NODES, 1024, 320);

  // layer 2: Din=1024, K=5120, F=1024, hA -> hB
  wcat_transpose_k<<<dim3(160, 32), dim3(32, 8), 0, stream>>>(W2, root2, WcatT, 4096, 1024, 5120);
  aggregate_k<<<N_NODES, 256, 0, stream>>>(hA, offs, cnt, inv, elist, Xcat, 1024, 5120);
  gemm_bt_bias_relu_k<<<dim3(8, 79), 256, 0, stream>>>(
      (const short*)Xcat, (const short*)WcatT, b2, hB, N_NODES, 1024, 5120);

  // layer 3: Din=1024, K=5120, F=712, hB -> hA (hA is dead, reuse)
  wcat_transpose_k<<<dim3(160, 23), dim3(32, 8), 0, stream>>>(W3, root3, WcatT, 4096, 712, 5120);
  aggregate_k<<<N_NODES, 256, 0, stream>>>(hB, offs, cnt, inv, elist, Xcat, 1024, 5120);
  gemm_bt_bias_relu_k<<<dim3(6, 79), 256, 0, stream>>>(
      (const short*)Xcat, (const short*)WcatT, b3, hA, N_NODES, 712, 5120);

  // pool + head
  pool_k<<<N_GRAPHS, 256, 0, stream>>>(hA, batch, g, N_NODES, 712);
  mlp_k<<<N_GRAPHS, 64, 0, stream>>>(g, fw1, fb1, fw2, fb2, out, 712);
}

// Round 2
// 778.188 us; speedup vs baseline: 1.3418x; 1.3418x over previous
//
#include <hip/hip_runtime.h>
#include <stdint.h>

#define N_NODES 10000
#define N_EDGES 160000
#define N_REL   4
#define N_GRAPHS 256
#define NBUCKET (N_NODES * N_REL)   // 40000 (dst,rel) buckets

typedef __attribute__((ext_vector_type(8))) short short8;
typedef __attribute__((ext_vector_type(4))) float float4v;

// ---------- helpers ----------
__device__ __forceinline__ unsigned short f2bf(float f) {
  unsigned int u = __float_as_uint(f);
  u = u + 0x7FFFu + ((u >> 16) & 1u);   // round-to-nearest-even
  return (unsigned short)(u >> 16);
}

__device__ __forceinline__ void g2lds16(const void* g, void* l) {
  // async global->LDS, 16B per lane; LDS dest = wave-uniform base + lane*16
  __builtin_amdgcn_global_load_lds(
      (const __attribute__((address_space(1))) void*)g,
      (__attribute__((address_space(3))) void*)l, 16, 0, 0);
}

__device__ __forceinline__ int lower_bound_i(const int* a, int n, int key) {
  int lo = 0, hi = n;
  while (lo < hi) { int mid = (lo + hi) >> 1; if (a[mid] < key) lo = mid + 1; else hi = mid; }
  return lo;
}

// ---------- CSR build ----------
__global__ void count_edges_k(const int* __restrict__ ei, const int* __restrict__ et,
                              int* __restrict__ cnt, int E) {
  int e = blockIdx.x * 256 + threadIdx.x;
  if (e < E) atomicAdd(&cnt[ei[E + e] * N_REL + et[e]], 1);
}

__global__ void scan_block_k(const int* __restrict__ cnt, int* __restrict__ eexcl,
                             int* __restrict__ btot, int n) {
  int i = blockIdx.x * 256 + threadIdx.x;
  int v = (i < n) ? cnt[i] : 0;
  int lane = threadIdx.x & 63, wv = threadIdx.x >> 6;
  int s = v;
  #pragma unroll
  for (int off = 1; off < 64; off <<= 1) {
    int t = __shfl_up(s, off, 64);
    if (lane >= off) s += t;
  }
  __shared__ int wt[4];
  if (lane == 63) wt[wv] = s;
  __syncthreads();
  int wadd = 0;
  for (int w = 0; w < wv; ++w) wadd += wt[w];
  int incl = s + wadd;
  if (i < n) eexcl[i] = incl - v;
  if (threadIdx.x == 255) btot[blockIdx.x] = incl;
}

__global__ void scan_final_k(const int* __restrict__ cnt, const int* __restrict__ eexcl,
                             const int* __restrict__ btot, int* __restrict__ offs,
                             int* __restrict__ cursor, float* __restrict__ inv, int n) {
  __shared__ int wred[4];
  __shared__ int sboff;
  int t = threadIdx.x;
  int part = (t < (int)blockIdx.x) ? btot[t] : 0;   // gridDim <= 256
  #pragma unroll
  for (int off = 32; off > 0; off >>= 1) part += __shfl_down(part, off, 64);
  if ((t & 63) == 0) wred[t >> 6] = part;
  __syncthreads();
  if (t == 0) sboff = wred[0] + wred[1] + wred[2] + wred[3];
  __syncthreads();
  int i = blockIdx.x * 256 + t;
  if (i < n) {
    int o = sboff + eexcl[i];
    offs[i] = o;
    cursor[i] = o;
    int c = cnt[i];
    inv[i] = 1.0f / (float)(c > 1 ? c : 1);
  }
}

__global__ void fill_csr_k(const int* __restrict__ ei, const int* __restrict__ et,
                           int* __restrict__ cursor, int* __restrict__ elist, int E) {
  int e = blockIdx.x * 256 + threadIdx.x;
  if (e >= E) return;
  int dst = ei[E + e], src = ei[e], r = et[e];
  int pos = atomicAdd(&cursor[dst * N_REL + r], 1);
  elist[pos] = src;
}

// ---------- Wcat build: [F][K] bf16, K = 5*Din, rows 0..4Din-1 from W, rest from root ----------
__global__ void wcat_transpose_k(const float* __restrict__ W, const float* __restrict__ root,
                                 unsigned short* __restrict__ out, int Din4, int F, int K) {
  __shared__ float tile[32][33];
  int kb = blockIdx.x * 32, fb = blockIdx.y * 32;
  for (int i = threadIdx.y; i < 32; i += 8) {
    int k = kb + i, f = fb + threadIdx.x;
    float v = 0.0f;
    if (k < K && f < F) v = (k < Din4) ? W[(size_t)k * F + f] : root[(size_t)(k - Din4) * F + f];
    tile[i][threadIdx.x] = v;
  }
  __syncthreads();
  for (int i = threadIdx.y; i < 32; i += 8) {
    int f = fb + i, k = kb + threadIdx.x;
    if (f < F && k < K) out[(size_t)f * K + k] = f2bf(tile[threadIdx.x][i]);
  }
}

// ---------- aggregation: Xcat[n] = [mean_r0 | mean_r1 | mean_r2 | mean_r3 | x[n]] in bf16 ----------
__global__ void aggregate_k(const float* __restrict__ x, const int* __restrict__ offs,
                            const int* __restrict__ cnt, const float* __restrict__ inv,
                            const int* __restrict__ elist, unsigned short* __restrict__ Xcat,
                            int Din, int K5) {
  int n = blockIdx.x;
  int tid = threadIdx.x;
  int c4 = Din >> 2;                       // float4 columns
  __shared__ int sid[256];
  for (int r = 0; r < N_REL; ++r) {
    int b = n * N_REL + r;
    int start = offs[b], c = cnt[b];
    float sc = inv[b];
    float4 acc = make_float4(0.f, 0.f, 0.f, 0.f);
    for (int base = 0; base < c; base += 256) {
      int m = min(256, c - base);
      __syncthreads();
      if (tid < m) sid[tid] = elist[start + base + tid];
      __syncthreads();
      if (tid < c4) {
        for (int j = 0; j < m; ++j) {
          float4 v = *((const float4*)(x + (size_t)sid[j] * Din) + tid);
          acc.x += v.x; acc.y += v.y; acc.z += v.z; acc.w += v.w;
        }
      }
    }
    if (tid < c4) {
      ushort4 o;
      o.x = f2bf(acc.x * sc); o.y = f2bf(acc.y * sc);
      o.z = f2bf(acc.z * sc); o.w = f2bf(acc.w * sc);
      *(ushort4*)&Xcat[(size_t)n * K5 + r * Din + tid * 4] = o;
    }
  }
  if (tid < c4) {  // root block: x itself
    float4 v = *((const float4*)(x + (size_t)n * Din) + tid);
    ushort4 o;
    o.x = f2bf(v.x); o.y = f2bf(v.y); o.z = f2bf(v.z); o.w = f2bf(v.w);
    *(ushort4*)&Xcat[(size_t)n * K5 + 4 * Din + tid * 4] = o;
  }
}

// ---------- GEMM: C[M,F] = relu(A[M,K](bf16) @ Bt[F,K]^T(bf16) + bias), m97 structure ----------
__global__ __launch_bounds__(256) void gemm_bt_bias_relu_k(
    const short* __restrict__ A, const short* __restrict__ Bt,
    const float* __restrict__ bias, float* __restrict__ C,
    int M, int Ndim, int K) {
  __shared__ short As[128 * 32];
  __shared__ short Bs[128 * 32];

  const int tid = threadIdx.x;
  const int wave = tid >> 6;
  const int lane = tid & 63;
  const int mBase = blockIdx.y * 128;
  const int nBase = blockIdx.x * 128;
  const int half = lane >> 4;     // k-quad 0..3
  const int lrow = lane & 15;
  const int wm = (wave >> 1) * 64;
  const int wn = (wave & 1) * 64;
  const int srow = lane >> 2;     // staging: row within wave's 16-row group
  const int schunk = lane & 3;    // staging: 16B chunk within 64B row

  float4v acc[4][4] = {};

  for (int k0 = 0; k0 < K; k0 += 32) {
    #pragma unroll
    for (int p = 0; p < 2; ++p) {
      int r = p * 64 + wave * 16 + srow;
      int gr = mBase + r; if (gr > M - 1) gr = M - 1;
      g2lds16(A + (size_t)gr * K + k0 + schunk * 8, &As[(p * 64 + wave * 16) * 32]);
      int gn = nBase + r; if (gn > Ndim - 1) gn = Ndim - 1;
      g2lds16(Bt + (size_t)gn * K + k0 + schunk * 8, &Bs[(p * 64 + wave * 16) * 32]);
    }
    __syncthreads();

    short8 a[4], b[4];
    #pragma unroll
    for (int i = 0; i < 4; ++i)
      a[i] = *(const short8*)&As[(wm + i * 16 + lrow) * 32 + half * 8];
    #pragma unroll
    for (int j = 0; j < 4; ++j)
      b[j] = *(const short8*)&Bs[(wn + j * 16 + lrow) * 32 + half * 8];
    #pragma unroll
    for (int i = 0; i < 4; ++i)
      #pragma unroll
      for (int j = 0; j < 4; ++j)
        acc[i][j] = __builtin_amdgcn_mfma_f32_16x16x32_bf16(a[i], b[j], acc[i][j], 0, 0, 0);
    __syncthreads();
  }

  #pragma unroll
  for (int i = 0; i < 4; ++i) {
    int row0 = mBase + wm + i * 16 + half * 4;
    #pragma unroll
    for (int j = 0; j < 4; ++j) {
      int col = nBase + wn + j * 16 + lrow;
      if (col < Ndim) {
        float bv = bias[col];
        #pragma unroll
        for (int r = 0; r < 4; ++r) {
          int rr = row0 + r;
          if (rr < M) C[(size_t)rr * Ndim + col] = fmaxf(acc[i][j][r] + bv, 0.0f);
        }
      }
    }
  }
}

// ---------- fused pool + head MLP: one block per graph ----------
// stage 1: g[712] = mean over node segment (float4-coalesced, into LDS)
// stage 2: hidden[64] = relu(fb1 + g @ fw1), 4 waves x 178-chunk split over F
// stage 3: out[gid] = hidden @ fw2 + fb2 (wave-0 shuffle reduce)
__global__ __launch_bounds__(256) void pool_mlp_k(
    const float* __restrict__ h, const int* __restrict__ batch,
    const float* __restrict__ fw1, const float* __restrict__ fb1,
    const float* __restrict__ fw2, const float* __restrict__ fb2,
    float* __restrict__ out, int N, int F) {
  __shared__ float gsh[712];
  __shared__ float part[4][64];

  const int gid = blockIdx.x;
  const int tid = threadIdx.x;
  const int lo = lower_bound_i(batch, N, gid);
  const int hi = lower_bound_i(batch, N, gid + 1);
  const float scale = (hi > lo) ? 1.0f / (float)(hi - lo) : 0.0f;
  const int C4 = F >> 2;  // 178

  // stage 1: pooled mean into LDS
  if (tid < C4) {
    float4 acc = make_float4(0.f, 0.f, 0.f, 0.f);
    int n = lo;
    for (; n + 1 < hi; n += 2) {
      float4 v0 = *((const float4*)(h + (size_t)n * F) + tid);
      float4 v1 = *((const float4*)(h + (size_t)(n + 1) * F) + tid);
      acc.x += v0.x + v1.x; acc.y += v0.y + v1.y;
      acc.z += v0.z + v1.z; acc.w += v0.w + v1.w;
    }
    if (n < hi) {
      float4 v0 = *((const float4*)(h + (size_t)n * F) + tid);
      acc.x += v0.x; acc.y += v0.y; acc.z += v0.z; acc.w += v0.w;
    }
    gsh[tid * 4 + 0] = acc.x * scale;
    gsh[tid * 4 + 1] = acc.y * scale;
    gsh[tid * 4 + 2] = acc.z * scale;
    gsh[tid * 4 + 3] = acc.w * scale;
  }
  __syncthreads();

  // stage 2: hidden-layer partial dot; f = lane, chunk = wave
  const int f = tid & 63;
  const int wv = tid >> 6;
  const int d0 = wv * 178;
  const int d1 = min(d0 + 178, F);
  float a = 0.0f;
  int d = d0;
  for (; d + 3 < d1; d += 4) {
    float g0 = gsh[d], g1 = gsh[d + 1], g2 = gsh[d + 2], g3 = gsh[d + 3];
    a += g0 * fw1[(size_t)d * 64 + f]
       + g1 * fw1[(size_t)(d + 1) * 64 + f]
       + g2 * fw1[(size_t)(d + 2) * 64 + f]
       + g3 * fw1[(size_t)(d + 3) * 64 + f];
  }
  for (; d < d1; ++d) a += gsh[d] * fw1[(size_t)d * 64 + f];
  part[wv][f] = a;
  __syncthreads();

  // stage 3: wave 0 reduces and finishes
  if (tid < 64) {
    float hsum = part[0][tid] + part[1][tid] + part[2][tid] + part[3][tid] + fb1[tid];
    hsum = fmaxf(hsum, 0.0f);
    float p = hsum * fw2[tid];
    #pragma unroll
    for (int off = 32; off > 0; off >>= 1) p += __shfl_down(p, off, 64);
    if (tid == 0) out[gid] = p + fb2[0];
  }
}

// ---------- launch ----------
extern "C" void kernel_launch(void* const* d_in, const int* in_sizes, int n_in,
                              void* d_out, int out_size, void* d_ws, size_t ws_size,
                              hipStream_t stream) {
  (void)in_sizes; (void)n_in; (void)out_size;
  const float* x    = (const float*)d_in[0];
  const int*  ei    = (const int*)d_in[1];
  const int*  et    = (const int*)d_in[2];
  const int*  batch = (const int*)d_in[3];
  const float* W1 = (const float*)d_in[4],  *root1 = (const float*)d_in[5],  *b1 = (const float*)d_in[6];
  const float* W2 = (const float*)d_in[7],  *root2 = (const float*)d_in[8],  *b2 = (const float*)d_in[9];
  const float* W3 = (const float*)d_in[10], *root3 = (const float*)d_in[11], *b3 = (const float*)d_in[12];
  const float* fw1 = (const float*)d_in[13], *fb1 = (const float*)d_in[14];
  const float* fw2 = (const float*)d_in[15], *fb2 = (const float*)d_in[16];
  float* out = (float*)d_out;

  // workspace layout (~197 MB)
  char* ws = (char*)d_ws;
  size_t off = 0;
  auto alloc = [&](size_t bytes) -> void* {
    void* p = ws + off; off += (bytes + 255) & ~(size_t)255; return p;
  };
  int*   cnt    = (int*)alloc(NBUCKET * 4);
  int*   offs   = (int*)alloc(NBUCKET * 4);
  int*   cursor = (int*)alloc(NBUCKET * 4);
  int*   eexcl  = (int*)alloc(NBUCKET * 4);
  int*   btot   = (int*)alloc(256 * 4);
  int*   elist  = (int*)alloc(N_EDGES * 4);
  float* inv    = (float*)alloc(NBUCKET * 4);
  unsigned short* Xcat  = (unsigned short*)alloc((size_t)N_NODES * 5120 * 2);
  unsigned short* WcatT = (unsigned short*)alloc((size_t)1024 * 5120 * 2);
  float* hA = (float*)alloc((size_t)N_NODES * 1024 * 4);
  float* hB = (float*)alloc((size_t)N_NODES * 1024 * 4);
  (void)ws_size;  // needs ~197 MB

  // CSR by (dst, rel)
  hipMemsetAsync(cnt, 0, NBUCKET * 4, stream);
  count_edges_k<<<(N_EDGES + 255) / 256, 256, 0, stream>>>(ei, et, cnt, N_EDGES);
  int nsb = (NBUCKET + 255) / 256;  // 157 blocks (<256)
  scan_block_k<<<nsb, 256, 0, stream>>>(cnt, eexcl, btot, NBUCKET);
  scan_final_k<<<nsb, 256, 0, stream>>>(cnt, eexcl, btot, offs, cursor, inv, NBUCKET);
  fill_csr_k<<<(N_EDGES + 255) / 256, 256, 0, stream>>>(ei, et, cursor, elist, N_EDGES);

  // layer 1: Din=64, K=320, F=1024, x -> hA
  wcat_transpose_k<<<dim3(10, 32), dim3(32, 8), 0, stream>>>(W1, root1, WcatT, 256, 1024, 320);
  aggregate_k<<<N_NODES, 256, 0, stream>>>(x, offs, cnt, inv, elist, Xcat, 64, 320);
  gemm_bt_bias_relu_k<<<dim3(8, 79), 256, 0, stream>>>(
      (const short*)Xcat, (const short*)WcatT, b1, hA, N_NODES, 1024, 320);

  // layer 2: Din=1024, K=5120, F=1024, hA -> hB
  wcat_transpose_k<<<dim3(160, 32), dim3(32, 8), 0, stream>>>(W2, root2, WcatT, 4096, 1024, 5120);
  aggregate_k<<<N_NODES, 256, 0, stream>>>(hA, offs, cnt, inv, elist, Xcat, 1024, 5120);
  gemm_bt_bias_relu_k<<<dim3(8, 79), 256, 0, stream>>>(
      (const short*)Xcat, (const short*)WcatT, b2, hB, N_NODES, 1024, 5120);

  // layer 3: Din=1024, K=5120, F=712, hB -> hA (hA is dead, reuse)
  wcat_transpose_k<<<dim3(160, 23), dim3(32, 8), 0, stream>>>(W3, root3, WcatT, 4096, 712, 5120);
  aggregate_k<<<N_NODES, 256, 0, stream>>>(hB, offs, cnt, inv, elist, Xcat, 1024, 5120);
  gemm_bt_bias_relu_k<<<dim3(6, 79), 256, 0, stream>>>(
      (const short*)Xcat, (const short*)WcatT, b3, hA, N_NODES, 712, 5120);

  // fused pool + head
  pool_mlp_k<<<N_GRAPHS, 256, 0, stream>>>(hA, batch, fw1, fb1, fw2, fb2, out,
                                           N_NODES, 712);
}

// Round 3
// 728.903 us; speedup vs baseline: 1.4326x; 1.0676x over previous
//
#include <hip/hip_runtime.h>
#include <stdint.h>

#define N_NODES 10000
#define N_EDGES 160000
#define N_REL   4
#define N_GRAPHS 256
#define NBUCKET (N_NODES * N_REL)   // 40000 (dst,rel) buckets

typedef __attribute__((ext_vector_type(8))) short short8;
typedef __attribute__((ext_vector_type(4))) float float4v;

// ---------- helpers ----------
__device__ __forceinline__ unsigned short f2bf(float f) {
  unsigned int u = __float_as_uint(f);
  u = u + 0x7FFFu + ((u >> 16) & 1u);   // round-to-nearest-even
  return (unsigned short)(u >> 16);
}
__device__ __forceinline__ float bf2f(unsigned short b) {
  return __uint_as_float(((unsigned int)b) << 16);
}

__device__ __forceinline__ void g2lds16(const void* g, void* l) {
  // async global->LDS, 16B per lane; LDS dest = wave-uniform base + lane*16
  __builtin_amdgcn_global_load_lds(
      (const __attribute__((address_space(1))) void*)g,
      (__attribute__((address_space(3))) void*)l, 16, 0, 0);
}

__device__ __forceinline__ int lower_bound_i(const int* a, int n, int key) {
  int lo = 0, hi = n;
  while (lo < hi) { int mid = (lo + hi) >> 1; if (a[mid] < key) lo = mid + 1; else hi = mid; }
  return lo;
}

// ---------- CSR build ----------
__global__ void count_edges_k(const int* __restrict__ ei, const int* __restrict__ et,
                              int* __restrict__ cnt, int E) {
  int e = blockIdx.x * 256 + threadIdx.x;
  if (e < E) atomicAdd(&cnt[ei[E + e] * N_REL + et[e]], 1);
}

__global__ void scan_block_k(const int* __restrict__ cnt, int* __restrict__ eexcl,
                             int* __restrict__ btot, int n) {
  int i = blockIdx.x * 256 + threadIdx.x;
  int v = (i < n) ? cnt[i] : 0;
  int lane = threadIdx.x & 63, wv = threadIdx.x >> 6;
  int s = v;
  #pragma unroll
  for (int off = 1; off < 64; off <<= 1) {
    int t = __shfl_up(s, off, 64);
    if (lane >= off) s += t;
  }
  __shared__ int wt[4];
  if (lane == 63) wt[wv] = s;
  __syncthreads();
  int wadd = 0;
  for (int w = 0; w < wv; ++w) wadd += wt[w];
  int incl = s + wadd;
  if (i < n) eexcl[i] = incl - v;
  if (threadIdx.x == 255) btot[blockIdx.x] = incl;
}

__global__ void scan_final_k(const int* __restrict__ cnt, const int* __restrict__ eexcl,
                             const int* __restrict__ btot, int* __restrict__ offs,
                             int* __restrict__ cursor, float* __restrict__ inv, int n) {
  __shared__ int wred[4];
  __shared__ int sboff;
  int t = threadIdx.x;
  int part = (t < (int)blockIdx.x) ? btot[t] : 0;   // gridDim <= 256
  #pragma unroll
  for (int off = 32; off > 0; off >>= 1) part += __shfl_down(part, off, 64);
  if ((t & 63) == 0) wred[t >> 6] = part;
  __syncthreads();
  if (t == 0) sboff = wred[0] + wred[1] + wred[2] + wred[3];
  __syncthreads();
  int i = blockIdx.x * 256 + t;
  if (i < n) {
    int o = sboff + eexcl[i];
    offs[i] = o;
    cursor[i] = o;
    int c = cnt[i];
    inv[i] = 1.0f / (float)(c > 1 ? c : 1);
  }
}

__global__ void fill_csr_k(const int* __restrict__ ei, const int* __restrict__ et,
                           int* __restrict__ cursor, int* __restrict__ elist, int E) {
  int e = blockIdx.x * 256 + threadIdx.x;
  if (e >= E) return;
  int dst = ei[E + e], src = ei[e], r = et[e];
  int pos = atomicAdd(&cursor[dst * N_REL + r], 1);
  elist[pos] = src;
}

// ---------- Wcat build: [F][K] bf16, K = 5*Din, rows 0..4Din-1 from W, rest from root ----------
__global__ void wcat_transpose_k(const float* __restrict__ W, const float* __restrict__ root,
                                 unsigned short* __restrict__ out, int Din4, int F, int K) {
  __shared__ float tile[32][33];
  int kb = blockIdx.x * 32, fb = blockIdx.y * 32;
  for (int i = threadIdx.y; i < 32; i += 8) {
    int k = kb + i, f = fb + threadIdx.x;
    float v = 0.0f;
    if (k < K && f < F) v = (k < Din4) ? W[(size_t)k * F + f] : root[(size_t)(k - Din4) * F + f];
    tile[i][threadIdx.x] = v;
  }
  __syncthreads();
  for (int i = threadIdx.y; i < 32; i += 8) {
    int f = fb + i, k = kb + threadIdx.x;
    if (f < F && k < K) out[(size_t)f * K + k] = f2bf(tile[threadIdx.x][i]);
  }
}

// ---------- layer-1 aggregation (Din=64, fp32 x): one wave per (node, rel) ----------
__global__ void aggregate64_k(const float* __restrict__ x, const int* __restrict__ offs,
                              const int* __restrict__ cnt, const float* __restrict__ inv,
                              const int* __restrict__ elist, unsigned short* __restrict__ Xcat) {
  const int n = blockIdx.x;
  const int wv = threadIdx.x >> 6;    // relation
  const int col = threadIdx.x & 63;
  const int b = n * N_REL + wv;
  const int start = offs[b], c = cnt[b];
  const float sc = inv[b];
  float acc = 0.0f;
  for (int j = 0; j < c; ++j) {
    int s = elist[start + j];          // wave-uniform scalar load
    acc += x[(size_t)s * 64 + col];
  }
  Xcat[(size_t)n * 320 + wv * 64 + col] = f2bf(acc * sc);
  if (wv == 0)
    Xcat[(size_t)n * 320 + 256 + col] = f2bf(x[(size_t)n * 64 + col]);
}

// ---------- aggregation (Din=1024, bf16 h): Xcat[n] = [mean_r0..mean_r3 | h[n]] ----------
__global__ void aggregate_bf16_k(const unsigned short* __restrict__ h,
                                 const int* __restrict__ offs, const int* __restrict__ cnt,
                                 const float* __restrict__ inv, const int* __restrict__ elist,
                                 unsigned short* __restrict__ Xcat) {
  const int n = blockIdx.x;
  const int tid = threadIdx.x;        // 256 threads, 4 bf16 cols each (ushort4, 8B)
  const int K5 = 5120, Din = 1024;
  __shared__ int sid[256];
  for (int r = 0; r < N_REL; ++r) {
    int b = n * N_REL + r;
    int start = offs[b], c = cnt[b];
    float sc = inv[b];
    float a0 = 0.f, a1 = 0.f, a2 = 0.f, a3 = 0.f;
    for (int base = 0; base < c; base += 256) {
      int m = min(256, c - base);
      __syncthreads();
      if (tid < m) sid[tid] = elist[start + base + tid];
      __syncthreads();
      for (int j = 0; j < m; ++j) {
        ushort4 v = *(const ushort4*)(h + (size_t)sid[j] * Din + tid * 4);
        a0 += bf2f(v.x); a1 += bf2f(v.y); a2 += bf2f(v.z); a3 += bf2f(v.w);
      }
    }
    ushort4 o;
    o.x = f2bf(a0 * sc); o.y = f2bf(a1 * sc); o.z = f2bf(a2 * sc); o.w = f2bf(a3 * sc);
    *(ushort4*)&Xcat[(size_t)n * K5 + r * Din + tid * 4] = o;
  }
  // root block: copy h[n] bits directly
  *(ushort4*)&Xcat[(size_t)n * K5 + 4 * Din + tid * 4] =
      *(const ushort4*)(h + (size_t)n * Din + tid * 4);
}

// ---------- GEMM: C[M,F](bf16) = relu(A[M,K](bf16) @ Bt[F,K]^T(bf16) + bias), BK=64 ----------
__global__ __launch_bounds__(256) void gemm_bt_bias_relu_k(
    const short* __restrict__ A, const short* __restrict__ Bt,
    const float* __restrict__ bias, unsigned short* __restrict__ C,
    int M, int Ndim, int K) {
  __shared__ short As[128 * 64];   // 16 KB
  __shared__ short Bs[128 * 64];   // 16 KB

  const int tid = threadIdx.x;
  const int wave = tid >> 6;
  const int lane = tid & 63;
  const int mBase = blockIdx.y * 128;
  const int nBase = blockIdx.x * 128;
  const int half = lane >> 4;     // k-quad 0..3
  const int lrow = lane & 15;
  const int wm = (wave >> 1) * 64;
  const int wn = (wave & 1) * 64;
  const int srow = lane >> 3;     // staging: row within 8-row group
  const int schunk = lane & 7;    // staging: 16B chunk within 128B row

  float4v acc[4][4] = {};

  for (int k0 = 0; k0 < K; k0 += 64) {
    #pragma unroll
    for (int p = 0; p < 4; ++p) {
      int rb = wave * 32 + p * 8;
      int r = rb + srow;
      int gr = mBase + r; if (gr > M - 1) gr = M - 1;
      g2lds16(A + (size_t)gr * K + k0 + schunk * 8, &As[rb * 64]);
      int gn = nBase + r; if (gn > Ndim - 1) gn = Ndim - 1;
      g2lds16(Bt + (size_t)gn * K + k0 + schunk * 8, &Bs[rb * 64]);
    }
    __syncthreads();

    #pragma unroll
    for (int kk = 0; kk < 2; ++kk) {
      short8 a[4], b[4];
      #pragma unroll
      for (int i = 0; i < 4; ++i)
        a[i] = *(const short8*)&As[(wm + i * 16 + lrow) * 64 + kk * 32 + half * 8];
      #pragma unroll
      for (int j = 0; j < 4; ++j)
        b[j] = *(const short8*)&Bs[(wn + j * 16 + lrow) * 64 + kk * 32 + half * 8];
      #pragma unroll
      for (int i = 0; i < 4; ++i)
        #pragma unroll
        for (int j = 0; j < 4; ++j)
          acc[i][j] = __builtin_amdgcn_mfma_f32_16x16x32_bf16(a[i], b[j], acc[i][j], 0, 0, 0);
    }
    __syncthreads();
  }

  #pragma unroll
  for (int i = 0; i < 4; ++i) {
    int row0 = mBase + wm + i * 16 + half * 4;
    #pragma unroll
    for (int j = 0; j < 4; ++j) {
      int col = nBase + wn + j * 16 + lrow;
      if (col < Ndim) {
        float bv = bias[col];
        #pragma unroll
        for (int r = 0; r < 4; ++r) {
          int rr = row0 + r;
          if (rr < M) C[(size_t)rr * Ndim + col] = f2bf(fmaxf(acc[i][j][r] + bv, 0.0f));
        }
      }
    }
  }
}

// ---------- fused pool + head MLP: one block per graph (bf16 h) ----------
__global__ __launch_bounds__(256) void pool_mlp_k(
    const unsigned short* __restrict__ h, const int* __restrict__ batch,
    const float* __restrict__ fw1, const float* __restrict__ fb1,
    const float* __restrict__ fw2, const float* __restrict__ fb2,
    float* __restrict__ out, int N, int F) {
  __shared__ float gsh[712];
  __shared__ float part[4][64];

  const int gid = blockIdx.x;
  const int tid = threadIdx.x;
  const int lo = lower_bound_i(batch, N, gid);
  const int hi = lower_bound_i(batch, N, gid + 1);
  const float scale = (hi > lo) ? 1.0f / (float)(hi - lo) : 0.0f;
  const int C4 = F >> 2;  // 178

  // stage 1: pooled mean into LDS
  if (tid < C4) {
    float a0 = 0.f, a1 = 0.f, a2 = 0.f, a3 = 0.f;
    for (int n = lo; n < hi; ++n) {
      ushort4 v = *(const ushort4*)(h + (size_t)n * F + tid * 4);
      a0 += bf2f(v.x); a1 += bf2f(v.y); a2 += bf2f(v.z); a3 += bf2f(v.w);
    }
    gsh[tid * 4 + 0] = a0 * scale;
    gsh[tid * 4 + 1] = a1 * scale;
    gsh[tid * 4 + 2] = a2 * scale;
    gsh[tid * 4 + 3] = a3 * scale;
  }
  __syncthreads();

  // stage 2: hidden-layer partial dot; f = lane, chunk = wave
  const int f = tid & 63;
  const int wv = tid >> 6;
  const int d0 = wv * 178;
  const int d1 = min(d0 + 178, F);
  float a = 0.0f;
  int d = d0;
  for (; d + 3 < d1; d += 4) {
    float g0 = gsh[d], g1 = gsh[d + 1], g2 = gsh[d + 2], g3 = gsh[d + 3];
    a += g0 * fw1[(size_t)d * 64 + f]
       + g1 * fw1[(size_t)(d + 1) * 64 + f]
       + g2 * fw1[(size_t)(d + 2) * 64 + f]
       + g3 * fw1[(size_t)(d + 3) * 64 + f];
  }
  for (; d < d1; ++d) a += gsh[d] * fw1[(size_t)d * 64 + f];
  part[wv][f] = a;
  __syncthreads();

  // stage 3: wave 0 reduces and finishes
  if (tid < 64) {
    float hsum = part[0][tid] + part[1][tid] + part[2][tid] + part[3][tid] + fb1[tid];
    hsum = fmaxf(hsum, 0.0f);
    float p = hsum * fw2[tid];
    #pragma unroll
    for (int off = 32; off > 0; off >>= 1) p += __shfl_down(p, off, 64);
    if (tid == 0) out[gid] = p + fb2[0];
  }
}

// ---------- launch ----------
extern "C" void kernel_launch(void* const* d_in, const int* in_sizes, int n_in,
                              void* d_out, int out_size, void* d_ws, size_t ws_size,
                              hipStream_t stream) {
  (void)in_sizes; (void)n_in; (void)out_size;
  const float* x    = (const float*)d_in[0];
  const int*  ei    = (const int*)d_in[1];
  const int*  et    = (const int*)d_in[2];
  const int*  batch = (const int*)d_in[3];
  const float* W1 = (const float*)d_in[4],  *root1 = (const float*)d_in[5],  *b1 = (const float*)d_in[6];
  const float* W2 = (const float*)d_in[7],  *root2 = (const float*)d_in[8],  *b2 = (const float*)d_in[9];
  const float* W3 = (const float*)d_in[10], *root3 = (const float*)d_in[11], *b3 = (const float*)d_in[12];
  const float* fw1 = (const float*)d_in[13], *fb1 = (const float*)d_in[14];
  const float* fw2 = (const float*)d_in[15], *fb2 = (const float*)d_in[16];
  float* out = (float*)d_out;

  // workspace layout (~155 MB)
  char* ws = (char*)d_ws;
  size_t off = 0;
  auto alloc = [&](size_t bytes) -> void* {
    void* p = ws + off; off += (bytes + 255) & ~(size_t)255; return p;
  };
  int*   cnt    = (int*)alloc(NBUCKET * 4);
  int*   offs   = (int*)alloc(NBUCKET * 4);
  int*   cursor = (int*)alloc(NBUCKET * 4);
  int*   eexcl  = (int*)alloc(NBUCKET * 4);
  int*   btot   = (int*)alloc(256 * 4);
  int*   elist  = (int*)alloc(N_EDGES * 4);
  float* inv    = (float*)alloc(NBUCKET * 4);
  unsigned short* Xcat  = (unsigned short*)alloc((size_t)N_NODES * 5120 * 2);
  unsigned short* WcatT = (unsigned short*)alloc((size_t)1024 * 5120 * 2);
  unsigned short* hA = (unsigned short*)alloc((size_t)N_NODES * 1024 * 2);
  unsigned short* hB = (unsigned short*)alloc((size_t)N_NODES * 1024 * 2);
  (void)ws_size;

  // CSR by (dst, rel)
  hipMemsetAsync(cnt, 0, NBUCKET * 4, stream);
  count_edges_k<<<(N_EDGES + 255) / 256, 256, 0, stream>>>(ei, et, cnt, N_EDGES);
  int nsb = (NBUCKET + 255) / 256;  // 157 blocks (<256)
  scan_block_k<<<nsb, 256, 0, stream>>>(cnt, eexcl, btot, NBUCKET);
  scan_final_k<<<nsb, 256, 0, stream>>>(cnt, eexcl, btot, offs, cursor, inv, NBUCKET);
  fill_csr_k<<<(N_EDGES + 255) / 256, 256, 0, stream>>>(ei, et, cursor, elist, N_EDGES);

  // layer 1: Din=64, K=320, F=1024, x -> hA
  wcat_transpose_k<<<dim3(10, 32), dim3(32, 8), 0, stream>>>(W1, root1, WcatT, 256, 1024, 320);
  aggregate64_k<<<N_NODES, 256, 0, stream>>>(x, offs, cnt, inv, elist, Xcat);
  gemm_bt_bias_relu_k<<<dim3(8, 79), 256, 0, stream>>>(
      (const short*)Xcat, (const short*)WcatT, b1, hA, N_NODES, 1024, 320);

  // layer 2: Din=1024, K=5120, F=1024, hA -> hB
  wcat_transpose_k<<<dim3(160, 32), dim3(32, 8), 0, stream>>>(W2, root2, WcatT, 4096, 1024, 5120);
  aggregate_bf16_k<<<N_NODES, 256, 0, stream>>>(hA, offs, cnt, inv, elist, Xcat);
  gemm_bt_bias_relu_k<<<dim3(8, 79), 256, 0, stream>>>(
      (const short*)Xcat, (const short*)WcatT, b2, hB, N_NODES, 1024, 5120);

  // layer 3: Din=1024, K=5120, F=712, hB -> hA (hA is dead, reuse)
  wcat_transpose_k<<<dim3(160, 23), dim3(32, 8), 0, stream>>>(W3, root3, WcatT, 4096, 712, 5120);
  aggregate_bf16_k<<<N_NODES, 256, 0, stream>>>(hB, offs, cnt, inv, elist, Xcat);
  gemm_bt_bias_relu_k<<<dim3(6, 79), 256, 0, stream>>>(
      (const short*)Xcat, (const short*)WcatT, b3, hA, N_NODES, 712, 5120);

  // fused pool + head
  pool_mlp_k<<<N_GRAPHS, 256, 0, stream>>>(hA, batch, fw1, fb1, fw2, fb2, out,
                                           N_NODES, 712);
}

// Round 4
// 602.573 us; speedup vs baseline: 1.7329x; 1.2097x over previous
//
#include <hip/hip_runtime.h>
#include <stdint.h>

#define N_NODES 10000
#define N_EDGES 160000
#define N_REL   4
#define N_GRAPHS 256
#define NBUCKET (N_NODES * N_REL)   // 40000 (dst,rel) buckets

typedef __attribute__((ext_vector_type(8))) short short8;
typedef __attribute__((ext_vector_type(4))) float float4v;

// ---------- helpers ----------
__device__ __forceinline__ unsigned short f2bf(float f) {
  unsigned int u = __float_as_uint(f);
  u = u + 0x7FFFu + ((u >> 16) & 1u);   // round-to-nearest-even
  return (unsigned short)(u >> 16);
}
__device__ __forceinline__ float bf2f(unsigned short b) {
  return __uint_as_float(((unsigned int)b) << 16);
}

__device__ __forceinline__ void g2lds16(const void* g, void* l) {
  // async global->LDS, 16B per lane; LDS dest = wave-uniform base + lane*16
  __builtin_amdgcn_global_load_lds(
      (const __attribute__((address_space(1))) void*)g,
      (__attribute__((address_space(3))) void*)l, 16, 0, 0);
}

__device__ __forceinline__ int lower_bound_i(const int* a, int n, int key) {
  int lo = 0, hi = n;
  while (lo < hi) { int mid = (lo + hi) >> 1; if (a[mid] < key) lo = mid + 1; else hi = mid; }
  return lo;
}

// ---------- CSR build ----------
__global__ void count_edges_k(const int* __restrict__ ei, const int* __restrict__ et,
                              int* __restrict__ cnt, int E) {
  int e = blockIdx.x * 256 + threadIdx.x;
  if (e < E) atomicAdd(&cnt[ei[E + e] * N_REL + et[e]], 1);
}

__global__ void scan_block_k(const int* __restrict__ cnt, int* __restrict__ eexcl,
                             int* __restrict__ btot, int n) {
  int i = blockIdx.x * 256 + threadIdx.x;
  int v = (i < n) ? cnt[i] : 0;
  int lane = threadIdx.x & 63, wv = threadIdx.x >> 6;
  int s = v;
  #pragma unroll
  for (int off = 1; off < 64; off <<= 1) {
    int t = __shfl_up(s, off, 64);
    if (lane >= off) s += t;
  }
  __shared__ int wt[4];
  if (lane == 63) wt[wv] = s;
  __syncthreads();
  int wadd = 0;
  for (int w = 0; w < wv; ++w) wadd += wt[w];
  int incl = s + wadd;
  if (i < n) eexcl[i] = incl - v;
  if (threadIdx.x == 255) btot[blockIdx.x] = incl;
}

__global__ void scan_final_k(const int* __restrict__ cnt, const int* __restrict__ eexcl,
                             const int* __restrict__ btot, int* __restrict__ offs,
                             int* __restrict__ cursor, float* __restrict__ inv, int n) {
  __shared__ int wred[4];
  __shared__ int sboff;
  int t = threadIdx.x;
  int part = (t < (int)blockIdx.x) ? btot[t] : 0;   // gridDim <= 256
  #pragma unroll
  for (int off = 32; off > 0; off >>= 1) part += __shfl_down(part, off, 64);
  if ((t & 63) == 0) wred[t >> 6] = part;
  __syncthreads();
  if (t == 0) sboff = wred[0] + wred[1] + wred[2] + wred[3];
  __syncthreads();
  int i = blockIdx.x * 256 + t;
  if (i < n) {
    int o = sboff + eexcl[i];
    offs[i] = o;
    cursor[i] = o;
    int c = cnt[i];
    inv[i] = 1.0f / (float)(c > 1 ? c : 1);
  }
}

__global__ void fill_csr_k(const int* __restrict__ ei, const int* __restrict__ et,
                           int* __restrict__ cursor, int* __restrict__ elist, int E) {
  int e = blockIdx.x * 256 + threadIdx.x;
  if (e >= E) return;
  int dst = ei[E + e], src = ei[e], r = et[e];
  int pos = atomicAdd(&cursor[dst * N_REL + r], 1);
  elist[pos] = src;
}

// ---------- Wcat build: [F][K] bf16, K = 5*Din, rows 0..4Din-1 from W, rest from root ----------
__global__ void wcat_transpose_k(const float* __restrict__ W, const float* __restrict__ root,
                                 unsigned short* __restrict__ out, int Din4, int F, int K) {
  __shared__ float tile[32][33];
  int kb = blockIdx.x * 32, fb = blockIdx.y * 32;
  for (int i = threadIdx.y; i < 32; i += 8) {
    int k = kb + i, f = fb + threadIdx.x;
    float v = 0.0f;
    if (k < K && f < F) v = (k < Din4) ? W[(size_t)k * F + f] : root[(size_t)(k - Din4) * F + f];
    tile[i][threadIdx.x] = v;
  }
  __syncthreads();
  for (int i = threadIdx.y; i < 32; i += 8) {
    int f = fb + i, k = kb + threadIdx.x;
    if (f < F && k < K) out[(size_t)f * K + k] = f2bf(tile[threadIdx.x][i]);
  }
}

// ---------- layer-1 aggregation (Din=64, fp32 x): one wave per (node, rel) ----------
__global__ void aggregate64_k(const float* __restrict__ x, const int* __restrict__ offs,
                              const int* __restrict__ cnt, const float* __restrict__ inv,
                              const int* __restrict__ elist, unsigned short* __restrict__ Xcat) {
  const int n = blockIdx.x;
  const int wv = threadIdx.x >> 6;    // relation
  const int col = threadIdx.x & 63;
  const int b = n * N_REL + wv;
  const int start = offs[b], c = cnt[b];
  const float sc = inv[b];
  float acc = 0.0f;
  for (int j = 0; j < c; ++j) {
    int s = elist[start + j];          // wave-uniform scalar load
    acc += x[(size_t)s * 64 + col];
  }
  Xcat[(size_t)n * 320 + wv * 64 + col] = f2bf(acc * sc);
  if (wv == 0)
    Xcat[(size_t)n * 320 + 256 + col] = f2bf(x[(size_t)n * 64 + col]);
}

// ---------- aggregation (Din=1024, bf16 h): Xcat[n] = [mean_r0..mean_r3 | h[n]] ----------
__global__ void aggregate_bf16_k(const unsigned short* __restrict__ h,
                                 const int* __restrict__ offs, const int* __restrict__ cnt,
                                 const float* __restrict__ inv, const int* __restrict__ elist,
                                 unsigned short* __restrict__ Xcat) {
  const int n = blockIdx.x;
  const int tid = threadIdx.x;        // 256 threads, 4 bf16 cols each (ushort4, 8B)
  const int K5 = 5120, Din = 1024;
  __shared__ int sid[256];
  for (int r = 0; r < N_REL; ++r) {
    int b = n * N_REL + r;
    int start = offs[b], c = cnt[b];
    float sc = inv[b];
    float a0 = 0.f, a1 = 0.f, a2 = 0.f, a3 = 0.f;
    for (int base = 0; base < c; base += 256) {
      int m = min(256, c - base);
      __syncthreads();
      if (tid < m) sid[tid] = elist[start + base + tid];
      __syncthreads();
      for (int j = 0; j < m; ++j) {
        ushort4 v = *(const ushort4*)(h + (size_t)sid[j] * Din + tid * 4);
        a0 += bf2f(v.x); a1 += bf2f(v.y); a2 += bf2f(v.z); a3 += bf2f(v.w);
      }
    }
    ushort4 o;
    o.x = f2bf(a0 * sc); o.y = f2bf(a1 * sc); o.z = f2bf(a2 * sc); o.w = f2bf(a3 * sc);
    *(ushort4*)&Xcat[(size_t)n * K5 + r * Din + tid * 4] = o;
  }
  // root block: copy h[n] bits directly
  *(ushort4*)&Xcat[(size_t)n * K5 + 4 * Din + tid * 4] =
      *(const ushort4*)(h + (size_t)n * Din + tid * 4);
}

// ---------- GEMM: C[M,F](bf16) = relu(A[M,K](bf16) @ Bt[F,K]^T(bf16) + bias) ----------
// BK=64, XOR-swizzled LDS: chunk c (16B) of row r lives at slot (c ^ (r&7)).
// Write side: global_load_lds lane l -> LDS slot l*16 in an 8-row/1KB wave
// region; lane fetches global chunk (l&7) ^ ((l>>3)&7) so layout matches.
// Read side: ds_read_b128 addr = r*128 + ((q ^ (r&7))*16); for 16 consecutive
// rows this spans all 32 banks at 2 lanes/bank -> conflict-free (m136).
__global__ __launch_bounds__(256) void gemm_bt_bias_relu_k(
    const short* __restrict__ A, const short* __restrict__ Bt,
    const float* __restrict__ bias, unsigned short* __restrict__ C,
    int M, int Ndim, int K) {
  __shared__ short As[128 * 64];   // 16 KB
  __shared__ short Bs[128 * 64];   // 16 KB

  const int tid = threadIdx.x;
  const int wave = tid >> 6;
  const int lane = tid & 63;
  const int mBase = blockIdx.y * 128;
  const int nBase = blockIdx.x * 128;
  const int half = lane >> 4;     // k-quad 0..3
  const int lrow = lane & 15;
  const int wm = (wave >> 1) * 64;
  const int wn = (wave & 1) * 64;
  const int srow = lane >> 3;               // staging: row within 8-row group
  const int schunk = (lane & 7) ^ srow;     // swizzle: global chunk for this slot

  float4v acc[4][4] = {};

  for (int k0 = 0; k0 < K; k0 += 64) {
    #pragma unroll
    for (int p = 0; p < 4; ++p) {
      int rb = wave * 32 + p * 8;
      int r = rb + srow;
      int gr = mBase + r; if (gr > M - 1) gr = M - 1;
      g2lds16(A + (size_t)gr * K + k0 + schunk * 8, &As[rb * 64]);
      int gn = nBase + r; if (gn > Ndim - 1) gn = Ndim - 1;
      g2lds16(Bt + (size_t)gn * K + k0 + schunk * 8, &Bs[rb * 64]);
    }
    __syncthreads();

    #pragma unroll
    for (int kk = 0; kk < 2; ++kk) {
      short8 a[4], b[4];
      #pragma unroll
      for (int i = 0; i < 4; ++i) {
        int r = wm + i * 16 + lrow;
        int q = (kk * 4 + half) ^ (r & 7);
        a[i] = *(const short8*)&As[r * 64 + q * 8];
      }
      #pragma unroll
      for (int j = 0; j < 4; ++j) {
        int r = wn + j * 16 + lrow;
        int q = (kk * 4 + half) ^ (r & 7);
        b[j] = *(const short8*)&Bs[r * 64 + q * 8];
      }
      #pragma unroll
      for (int i = 0; i < 4; ++i)
        #pragma unroll
        for (int j = 0; j < 4; ++j)
          acc[i][j] = __builtin_amdgcn_mfma_f32_16x16x32_bf16(a[i], b[j], acc[i][j], 0, 0, 0);
    }
    __syncthreads();
  }

  #pragma unroll
  for (int i = 0; i < 4; ++i) {
    int row0 = mBase + wm + i * 16 + half * 4;
    #pragma unroll
    for (int j = 0; j < 4; ++j) {
      int col = nBase + wn + j * 16 + lrow;
      if (col < Ndim) {
        float bv = bias[col];
        #pragma unroll
        for (int r = 0; r < 4; ++r) {
          int rr = row0 + r;
          if (rr < M) C[(size_t)rr * Ndim + col] = f2bf(fmaxf(acc[i][j][r] + bv, 0.0f));
        }
      }
    }
  }
}

// ---------- fused pool + head MLP: one block per graph (bf16 h) ----------
__global__ __launch_bounds__(256) void pool_mlp_k(
    const unsigned short* __restrict__ h, const int* __restrict__ batch,
    const float* __restrict__ fw1, const float* __restrict__ fb1,
    const float* __restrict__ fw2, const float* __restrict__ fb2,
    float* __restrict__ out, int N, int F) {
  __shared__ float gsh[712];
  __shared__ float part[4][64];

  const int gid = blockIdx.x;
  const int tid = threadIdx.x;
  const int lo = lower_bound_i(batch, N, gid);
  const int hi = lower_bound_i(batch, N, gid + 1);
  const float scale = (hi > lo) ? 1.0f / (float)(hi - lo) : 0.0f;
  const int C4 = F >> 2;  // 178

  // stage 1: pooled mean into LDS
  if (tid < C4) {
    float a0 = 0.f, a1 = 0.f, a2 = 0.f, a3 = 0.f;
    for (int n = lo; n < hi; ++n) {
      ushort4 v = *(const ushort4*)(h + (size_t)n * F + tid * 4);
      a0 += bf2f(v.x); a1 += bf2f(v.y); a2 += bf2f(v.z); a3 += bf2f(v.w);
    }
    gsh[tid * 4 + 0] = a0 * scale;
    gsh[tid * 4 + 1] = a1 * scale;
    gsh[tid * 4 + 2] = a2 * scale;
    gsh[tid * 4 + 3] = a3 * scale;
  }
  __syncthreads();

  // stage 2: hidden-layer partial dot; f = lane, chunk = wave
  const int f = tid & 63;
  const int wv = tid >> 6;
  const int d0 = wv * 178;
  const int d1 = min(d0 + 178, F);
  float a = 0.0f;
  int d = d0;
  for (; d + 3 < d1; d += 4) {
    float g0 = gsh[d], g1 = gsh[d + 1], g2 = gsh[d + 2], g3 = gsh[d + 3];
    a += g0 * fw1[(size_t)d * 64 + f]
       + g1 * fw1[(size_t)(d + 1) * 64 + f]
       + g2 * fw1[(size_t)(d + 2) * 64 + f]
       + g3 * fw1[(size_t)(d + 3) * 64 + f];
  }
  for (; d < d1; ++d) a += gsh[d] * fw1[(size_t)d * 64 + f];
  part[wv][f] = a;
  __syncthreads();

  // stage 3: wave 0 reduces and finishes
  if (tid < 64) {
    float hsum = part[0][tid] + part[1][tid] + part[2][tid] + part[3][tid] + fb1[tid];
    hsum = fmaxf(hsum, 0.0f);
    float p = hsum * fw2[tid];
    #pragma unroll
    for (int off = 32; off > 0; off >>= 1) p += __shfl_down(p, off, 64);
    if (tid == 0) out[gid] = p + fb2[0];
  }
}

// ---------- launch ----------
extern "C" void kernel_launch(void* const* d_in, const int* in_sizes, int n_in,
                              void* d_out, int out_size, void* d_ws, size_t ws_size,
                              hipStream_t stream) {
  (void)in_sizes; (void)n_in; (void)out_size;
  const float* x    = (const float*)d_in[0];
  const int*  ei    = (const int*)d_in[1];
  const int*  et    = (const int*)d_in[2];
  const int*  batch = (const int*)d_in[3];
  const float* W1 = (const float*)d_in[4],  *root1 = (const float*)d_in[5],  *b1 = (const float*)d_in[6];
  const float* W2 = (const float*)d_in[7],  *root2 = (const float*)d_in[8],  *b2 = (const float*)d_in[9];
  const float* W3 = (const float*)d_in[10], *root3 = (const float*)d_in[11], *b3 = (const float*)d_in[12];
  const float* fw1 = (const float*)d_in[13], *fb1 = (const float*)d_in[14];
  const float* fw2 = (const float*)d_in[15], *fb2 = (const float*)d_in[16];
  float* out = (float*)d_out;

  // workspace layout (~155 MB)
  char* ws = (char*)d_ws;
  size_t off = 0;
  auto alloc = [&](size_t bytes) -> void* {
    void* p = ws + off; off += (bytes + 255) & ~(size_t)255; return p;
  };
  int*   cnt    = (int*)alloc(NBUCKET * 4);
  int*   offs   = (int*)alloc(NBUCKET * 4);
  int*   cursor = (int*)alloc(NBUCKET * 4);
  int*   eexcl  = (int*)alloc(NBUCKET * 4);
  int*   btot   = (int*)alloc(256 * 4);
  int*   elist  = (int*)alloc(N_EDGES * 4);
  float* inv    = (float*)alloc(NBUCKET * 4);
  unsigned short* Xcat  = (unsigned short*)alloc((size_t)N_NODES * 5120 * 2);
  unsigned short* WcatT = (unsigned short*)alloc((size_t)1024 * 5120 * 2);
  unsigned short* hA = (unsigned short*)alloc((size_t)N_NODES * 1024 * 2);
  unsigned short* hB = (unsigned short*)alloc((size_t)N_NODES * 1024 * 2);
  (void)ws_size;

  // CSR by (dst, rel)
  hipMemsetAsync(cnt, 0, NBUCKET * 4, stream);
  count_edges_k<<<(N_EDGES + 255) / 256, 256, 0, stream>>>(ei, et, cnt, N_EDGES);
  int nsb = (NBUCKET + 255) / 256;  // 157 blocks (<256)
  scan_block_k<<<nsb, 256, 0, stream>>>(cnt, eexcl, btot, NBUCKET);
  scan_final_k<<<nsb, 256, 0, stream>>>(cnt, eexcl, btot, offs, cursor, inv, NBUCKET);
  fill_csr_k<<<(N_EDGES + 255) / 256, 256, 0, stream>>>(ei, et, cursor, elist, N_EDGES);

  // layer 1: Din=64, K=320, F=1024, x -> hA
  wcat_transpose_k<<<dim3(10, 32), dim3(32, 8), 0, stream>>>(W1, root1, WcatT, 256, 1024, 320);
  aggregate64_k<<<N_NODES, 256, 0, stream>>>(x, offs, cnt, inv, elist, Xcat);
  gemm_bt_bias_relu_k<<<dim3(8, 79), 256, 0, stream>>>(
      (const short*)Xcat, (const short*)WcatT, b1, hA, N_NODES, 1024, 320);

  // layer 2: Din=1024, K=5120, F=1024, hA -> hB
  wcat_transpose_k<<<dim3(160, 32), dim3(32, 8), 0, stream>>>(W2, root2, WcatT, 4096, 1024, 5120);
  aggregate_bf16_k<<<N_NODES, 256, 0, stream>>>(hA, offs, cnt, inv, elist, Xcat);
  gemm_bt_bias_relu_k<<<dim3(8, 79), 256, 0, stream>>>(
      (const short*)Xcat, (const short*)WcatT, b2, hB, N_NODES, 1024, 5120);

  // layer 3: Din=1024, K=5120, F=712, hB -> hA (hA is dead, reuse)
  wcat_transpose_k<<<dim3(160, 23), dim3(32, 8), 0, stream>>>(W3, root3, WcatT, 4096, 712, 5120);
  aggregate_bf16_k<<<N_NODES, 256, 0, stream>>>(hB, offs, cnt, inv, elist, Xcat);
  gemm_bt_bias_relu_k<<<dim3(6, 79), 256, 0, stream>>>(
      (const short*)Xcat, (const short*)WcatT, b3, hA, N_NODES, 712, 5120);

  // fused pool + head
  pool_mlp_k<<<N_GRAPHS, 256, 0, stream>>>(hA, batch, fw1, fb1, fw2, fb2, out,
                                           N_NODES, 712);
}

// Round 5
// 551.523 us; speedup vs baseline: 1.8933x; 1.0926x over previous
//
#include <hip/hip_runtime.h>
#include <stdint.h>

#define N_NODES 10000
#define N_EDGES 160000
#define N_REL   4
#define N_GRAPHS 256
#define NBUCKET (N_NODES * N_REL)   // 40000 (dst,rel) buckets

typedef __attribute__((ext_vector_type(8))) short short8;
typedef __attribute__((ext_vector_type(4))) float float4v;

// ---------- helpers ----------
__device__ __forceinline__ unsigned short f2bf(float f) {
  unsigned int u = __float_as_uint(f);
  u = u + 0x7FFFu + ((u >> 16) & 1u);   // round-to-nearest-even
  return (unsigned short)(u >> 16);
}
__device__ __forceinline__ float bf2f(unsigned short b) {
  return __uint_as_float(((unsigned int)b) << 16);
}

__device__ __forceinline__ void g2lds16(const void* g, void* l) {
  // async global->LDS, 16B per lane; LDS dest = wave-uniform base + lane*16
  __builtin_amdgcn_global_load_lds(
      (const __attribute__((address_space(1))) void*)g,
      (__attribute__((address_space(3))) void*)l, 16, 0, 0);
}

__device__ __forceinline__ int lower_bound_i(const int* a, int n, int key) {
  int lo = 0, hi = n;
  while (lo < hi) { int mid = (lo + hi) >> 1; if (a[mid] < key) lo = mid + 1; else hi = mid; }
  return lo;
}

// ---------- CSR build ----------
__global__ void count_edges_k(const int* __restrict__ ei, const int* __restrict__ et,
                              int* __restrict__ cnt, int E) {
  int e = blockIdx.x * 256 + threadIdx.x;
  if (e < E) atomicAdd(&cnt[ei[E + e] * N_REL + et[e]], 1);
}

__global__ void scan_block_k(const int* __restrict__ cnt, int* __restrict__ eexcl,
                             int* __restrict__ btot, int n) {
  int i = blockIdx.x * 256 + threadIdx.x;
  int v = (i < n) ? cnt[i] : 0;
  int lane = threadIdx.x & 63, wv = threadIdx.x >> 6;
  int s = v;
  #pragma unroll
  for (int off = 1; off < 64; off <<= 1) {
    int t = __shfl_up(s, off, 64);
    if (lane >= off) s += t;
  }
  __shared__ int wt[4];
  if (lane == 63) wt[wv] = s;
  __syncthreads();
  int wadd = 0;
  for (int w = 0; w < wv; ++w) wadd += wt[w];
  int incl = s + wadd;
  if (i < n) eexcl[i] = incl - v;
  if (threadIdx.x == 255) btot[blockIdx.x] = incl;
}

__global__ void scan_final_k(const int* __restrict__ cnt, const int* __restrict__ eexcl,
                             const int* __restrict__ btot, int* __restrict__ offs,
                             int* __restrict__ cursor, float* __restrict__ inv, int n) {
  __shared__ int wred[4];
  __shared__ int sboff;
  int t = threadIdx.x;
  int part = (t < (int)blockIdx.x) ? btot[t] : 0;   // gridDim <= 256
  #pragma unroll
  for (int off = 32; off > 0; off >>= 1) part += __shfl_down(part, off, 64);
  if ((t & 63) == 0) wred[t >> 6] = part;
  __syncthreads();
  if (t == 0) sboff = wred[0] + wred[1] + wred[2] + wred[3];
  __syncthreads();
  int i = blockIdx.x * 256 + t;
  if (i < n) {
    int o = sboff + eexcl[i];
    offs[i] = o;
    cursor[i] = o;
    int c = cnt[i];
    inv[i] = 1.0f / (float)(c > 1 ? c : 1);
  }
}

__global__ void fill_csr_k(const int* __restrict__ ei, const int* __restrict__ et,
                           int* __restrict__ cursor, int* __restrict__ elist, int E) {
  int e = blockIdx.x * 256 + threadIdx.x;
  if (e >= E) return;
  int dst = ei[E + e], src = ei[e], r = et[e];
  int pos = atomicAdd(&cursor[dst * N_REL + r], 1);
  elist[pos] = src;
}

// ---------- Wcat build: [F][K] bf16, K = 5*Din, rows 0..4Din-1 from W, rest from root ----------
__global__ void wcat_transpose_k(const float* __restrict__ W, const float* __restrict__ root,
                                 unsigned short* __restrict__ out, int Din4, int F, int K) {
  __shared__ float tile[32][33];
  int kb = blockIdx.x * 32, fb = blockIdx.y * 32;
  for (int i = threadIdx.y; i < 32; i += 8) {
    int k = kb + i, f = fb + threadIdx.x;
    float v = 0.0f;
    if (k < K && f < F) v = (k < Din4) ? W[(size_t)k * F + f] : root[(size_t)(k - Din4) * F + f];
    tile[i][threadIdx.x] = v;
  }
  __syncthreads();
  for (int i = threadIdx.y; i < 32; i += 8) {
    int f = fb + i, k = kb + threadIdx.x;
    if (f < F && k < K) out[(size_t)f * K + k] = f2bf(tile[threadIdx.x][i]);
  }
}

// ---------- layer-1 aggregation (Din=64, fp32 x): one wave per (node, rel) ----------
__global__ void aggregate64_k(const float* __restrict__ x, const int* __restrict__ offs,
                              const int* __restrict__ cnt, const float* __restrict__ inv,
                              const int* __restrict__ elist, unsigned short* __restrict__ Xcat) {
  const int n = blockIdx.x;
  const int wv = threadIdx.x >> 6;    // relation
  const int col = threadIdx.x & 63;
  const int b = n * N_REL + wv;
  const int start = offs[b], c = cnt[b];
  const float sc = inv[b];
  float acc = 0.0f;
  for (int j = 0; j < c; ++j) {
    int s = elist[start + j];          // wave-uniform scalar load
    acc += x[(size_t)s * 64 + col];
  }
  Xcat[(size_t)n * 320 + wv * 64 + col] = f2bf(acc * sc);
  if (wv == 0)
    Xcat[(size_t)n * 320 + 256 + col] = f2bf(x[(size_t)n * 64 + col]);
}

// ---------- aggregation (Din=1024, bf16 h), column-sliced for L2 residency ----------
// grid: 40000 one-wave blocks. chunk = (bid&7)>>1 pins each 256-col slice
// (10000x256x2B = 5.1 MB) to an XCD *pair* (heuristic: XCD = bid % 8), so the
// slice stays L2-resident instead of thrashing all 8 L2s with the full 20.5 MB.
// node = (bid>>3)*2 + (bid&1). Per-relation segmented loops (elist is sorted
// by bucket) keep accumulators static; summation order identical to before.
__global__ __launch_bounds__(64) void aggregate_bf16_k(
    const unsigned short* __restrict__ h,
    const int* __restrict__ offs, const int* __restrict__ cnt,
    const float* __restrict__ inv, const int* __restrict__ elist,
    unsigned short* __restrict__ Xcat) {
  const int bid = blockIdx.x;
  const int chunk = (bid & 7) >> 1;
  const int n = ((bid >> 3) << 1) | (bid & 1);
  const int lane = threadIdx.x;                 // 64
  const int col = chunk * 256 + lane * 4;       // 4 bf16 cols per lane (8B)
  const int Din = 1024, K5 = 5120;
  const int b0 = n * N_REL;
  const int start = offs[b0];
  const int c0 = cnt[b0], c1 = cnt[b0 + 1], c2 = cnt[b0 + 2], c3 = cnt[b0 + 3];
  int pr[5];
  pr[0] = 0; pr[1] = c0; pr[2] = pr[1] + c1; pr[3] = pr[2] + c2; pr[4] = pr[3] + c3;
  const int cTot = pr[4];

  float ax[4] = {0.f, 0.f, 0.f, 0.f};
  float ay[4] = {0.f, 0.f, 0.f, 0.f};
  float az[4] = {0.f, 0.f, 0.f, 0.f};
  float aw[4] = {0.f, 0.f, 0.f, 0.f};

  __shared__ int sid[64];
  for (int base = 0; base < cTot; base += 64) {
    int m = min(64, cTot - base);
    __syncthreads();
    if (lane < m) sid[lane] = elist[start + base + lane];
    __syncthreads();
    #pragma unroll
    for (int r = 0; r < N_REL; ++r) {
      int lo = max(pr[r] - base, 0);
      int hi = min(pr[r + 1] - base, m);
      for (int j = lo; j < hi; ++j) {
        ushort4 v = *(const ushort4*)(h + (size_t)sid[j] * Din + col);
        ax[r] += bf2f(v.x); ay[r] += bf2f(v.y);
        az[r] += bf2f(v.z); aw[r] += bf2f(v.w);
      }
    }
  }

  #pragma unroll
  for (int r = 0; r < N_REL; ++r) {
    float sc = inv[b0 + r];
    ushort4 o;
    o.x = f2bf(ax[r] * sc); o.y = f2bf(ay[r] * sc);
    o.z = f2bf(az[r] * sc); o.w = f2bf(aw[r] * sc);
    *(ushort4*)&Xcat[(size_t)n * K5 + r * Din + col] = o;
  }
  // root block: copy h[n] bits directly
  *(ushort4*)&Xcat[(size_t)n * K5 + 4 * Din + col] =
      *(const ushort4*)(h + (size_t)n * Din + col);
}

// ---------- GEMM: C[M,F](bf16) = relu(A[M,K](bf16) @ Bt[F,K]^T(bf16) + bias) ----------
// BK=64, XOR-swizzled LDS (conflict-free, verified R4: SQ_LDS_BANK_CONFLICT=0).
// 1D grid = NX*80 blocks, XCD-banded mapping: xcd = bid%8 owns 10 contiguous
// row-strips x all NX columns, so each A-strip is fetched once per XCD and
// reused NX times from its L2 (A was being refetched ~4x across XCDs in R4:
// FETCH 408 MB vs 133 MB ideal).
__global__ __launch_bounds__(256) void gemm_bt_bias_relu_k(
    const short* __restrict__ A, const short* __restrict__ Bt,
    const float* __restrict__ bias, unsigned short* __restrict__ C,
    int M, int Ndim, int K, int NX) {
  __shared__ short As[128 * 64];   // 16 KB
  __shared__ short Bs[128 * 64];   // 16 KB

  const int bid = blockIdx.x;
  const int xcd = bid & 7;
  const int local = bid >> 3;              // [0, NX*10)
  const int t = xcd * (NX * 10) + local;   // contiguous tile band per XCD
  const int tileM = t / NX;                // [0, 80)
  const int tileN = t - tileM * NX;
  const int mBase = tileM * 128;
  const int nBase = tileN * 128;

  const int tid = threadIdx.x;
  const int wave = tid >> 6;
  const int lane = tid & 63;
  const int half = lane >> 4;     // k-quad 0..3
  const int lrow = lane & 15;
  const int wm = (wave >> 1) * 64;
  const int wn = (wave & 1) * 64;
  const int srow = lane >> 3;               // staging: row within 8-row group
  const int schunk = (lane & 7) ^ srow;     // swizzle: global chunk for this slot

  float4v acc[4][4] = {};

  for (int k0 = 0; k0 < K; k0 += 64) {
    #pragma unroll
    for (int p = 0; p < 4; ++p) {
      int rb = wave * 32 + p * 8;
      int r = rb + srow;
      int gr = mBase + r; if (gr > M - 1) gr = M - 1;
      g2lds16(A + (size_t)gr * K + k0 + schunk * 8, &As[rb * 64]);
      int gn = nBase + r; if (gn > Ndim - 1) gn = Ndim - 1;
      g2lds16(Bt + (size_t)gn * K + k0 + schunk * 8, &Bs[rb * 64]);
    }
    __syncthreads();

    #pragma unroll
    for (int kk = 0; kk < 2; ++kk) {
      short8 a[4], b[4];
      #pragma unroll
      for (int i = 0; i < 4; ++i) {
        int r = wm + i * 16 + lrow;
        int q = (kk * 4 + half) ^ (r & 7);
        a[i] = *(const short8*)&As[r * 64 + q * 8];
      }
      #pragma unroll
      for (int j = 0; j < 4; ++j) {
        int r = wn + j * 16 + lrow;
        int q = (kk * 4 + half) ^ (r & 7);
        b[j] = *(const short8*)&Bs[r * 64 + q * 8];
      }
      #pragma unroll
      for (int i = 0; i < 4; ++i)
        #pragma unroll
        for (int j = 0; j < 4; ++j)
          acc[i][j] = __builtin_amdgcn_mfma_f32_16x16x32_bf16(a[i], b[j], acc[i][j], 0, 0, 0);
    }
    __syncthreads();
  }

  #pragma unroll
  for (int i = 0; i < 4; ++i) {
    int row0 = mBase + wm + i * 16 + half * 4;
    #pragma unroll
    for (int j = 0; j < 4; ++j) {
      int col = nBase + wn + j * 16 + lrow;
      if (col < Ndim) {
        float bv = bias[col];
        #pragma unroll
        for (int r = 0; r < 4; ++r) {
          int rr = row0 + r;
          if (rr < M) C[(size_t)rr * Ndim + col] = f2bf(fmaxf(acc[i][j][r] + bv, 0.0f));
        }
      }
    }
  }
}

// ---------- fused pool + head MLP: one block per graph (bf16 h) ----------
__global__ __launch_bounds__(256) void pool_mlp_k(
    const unsigned short* __restrict__ h, const int* __restrict__ batch,
    const float* __restrict__ fw1, const float* __restrict__ fb1,
    const float* __restrict__ fw2, const float* __restrict__ fb2,
    float* __restrict__ out, int N, int F) {
  __shared__ float gsh[712];
  __shared__ float part[4][64];

  const int gid = blockIdx.x;
  const int tid = threadIdx.x;
  const int lo = lower_bound_i(batch, N, gid);
  const int hi = lower_bound_i(batch, N, gid + 1);
  const float scale = (hi > lo) ? 1.0f / (float)(hi - lo) : 0.0f;
  const int C4 = F >> 2;  // 178

  // stage 1: pooled mean into LDS
  if (tid < C4) {
    float a0 = 0.f, a1 = 0.f, a2 = 0.f, a3 = 0.f;
    for (int n = lo; n < hi; ++n) {
      ushort4 v = *(const ushort4*)(h + (size_t)n * F + tid * 4);
      a0 += bf2f(v.x); a1 += bf2f(v.y); a2 += bf2f(v.z); a3 += bf2f(v.w);
    }
    gsh[tid * 4 + 0] = a0 * scale;
    gsh[tid * 4 + 1] = a1 * scale;
    gsh[tid * 4 + 2] = a2 * scale;
    gsh[tid * 4 + 3] = a3 * scale;
  }
  __syncthreads();

  // stage 2: hidden-layer partial dot; f = lane, chunk = wave
  const int f = tid & 63;
  const int wv = tid >> 6;
  const int d0 = wv * 178;
  const int d1 = min(d0 + 178, F);
  float a = 0.0f;
  int d = d0;
  for (; d + 3 < d1; d += 4) {
    float g0 = gsh[d], g1 = gsh[d + 1], g2 = gsh[d + 2], g3 = gsh[d + 3];
    a += g0 * fw1[(size_t)d * 64 + f]
       + g1 * fw1[(size_t)(d + 1) * 64 + f]
       + g2 * fw1[(size_t)(d + 2) * 64 + f]
       + g3 * fw1[(size_t)(d + 3) * 64 + f];
  }
  for (; d < d1; ++d) a += gsh[d] * fw1[(size_t)d * 64 + f];
  part[wv][f] = a;
  __syncthreads();

  // stage 3: wave 0 reduces and finishes
  if (tid < 64) {
    float hsum = part[0][tid] + part[1][tid] + part[2][tid] + part[3][tid] + fb1[tid];
    hsum = fmaxf(hsum, 0.0f);
    float p = hsum * fw2[tid];
    #pragma unroll
    for (int off = 32; off > 0; off >>= 1) p += __shfl_down(p, off, 64);
    if (tid == 0) out[gid] = p + fb2[0];
  }
}

// ---------- launch ----------
extern "C" void kernel_launch(void* const* d_in, const int* in_sizes, int n_in,
                              void* d_out, int out_size, void* d_ws, size_t ws_size,
                              hipStream_t stream) {
  (void)in_sizes; (void)n_in; (void)out_size;
  const float* x    = (const float*)d_in[0];
  const int*  ei    = (const int*)d_in[1];
  const int*  et    = (const int*)d_in[2];
  const int*  batch = (const int*)d_in[3];
  const float* W1 = (const float*)d_in[4],  *root1 = (const float*)d_in[5],  *b1 = (const float*)d_in[6];
  const float* W2 = (const float*)d_in[7],  *root2 = (const float*)d_in[8],  *b2 = (const float*)d_in[9];
  const float* W3 = (const float*)d_in[10], *root3 = (const float*)d_in[11], *b3 = (const float*)d_in[12];
  const float* fw1 = (const float*)d_in[13], *fb1 = (const float*)d_in[14];
  const float* fw2 = (const float*)d_in[15], *fb2 = (const float*)d_in[16];
  float* out = (float*)d_out;

  // workspace layout (~155 MB)
  char* ws = (char*)d_ws;
  size_t off = 0;
  auto alloc = [&](size_t bytes) -> void* {
    void* p = ws + off; off += (bytes + 255) & ~(size_t)255; return p;
  };
  int*   cnt    = (int*)alloc(NBUCKET * 4);
  int*   offs   = (int*)alloc(NBUCKET * 4);
  int*   cursor = (int*)alloc(NBUCKET * 4);
  int*   eexcl  = (int*)alloc(NBUCKET * 4);
  int*   btot   = (int*)alloc(256 * 4);
  int*   elist  = (int*)alloc(N_EDGES * 4);
  float* inv    = (float*)alloc(NBUCKET * 4);
  unsigned short* Xcat  = (unsigned short*)alloc((size_t)N_NODES * 5120 * 2);
  unsigned short* WcatT = (unsigned short*)alloc((size_t)1024 * 5120 * 2);
  unsigned short* hA = (unsigned short*)alloc((size_t)N_NODES * 1024 * 2);
  unsigned short* hB = (unsigned short*)alloc((size_t)N_NODES * 1024 * 2);
  (void)ws_size;

  // CSR by (dst, rel)
  hipMemsetAsync(cnt, 0, NBUCKET * 4, stream);
  count_edges_k<<<(N_EDGES + 255) / 256, 256, 0, stream>>>(ei, et, cnt, N_EDGES);
  int nsb = (NBUCKET + 255) / 256;  // 157 blocks (<256)
  scan_block_k<<<nsb, 256, 0, stream>>>(cnt, eexcl, btot, NBUCKET);
  scan_final_k<<<nsb, 256, 0, stream>>>(cnt, eexcl, btot, offs, cursor, inv, NBUCKET);
  fill_csr_k<<<(N_EDGES + 255) / 256, 256, 0, stream>>>(ei, et, cursor, elist, N_EDGES);

  // layer 1: Din=64, K=320, F=1024, x -> hA
  wcat_transpose_k<<<dim3(10, 32), dim3(32, 8), 0, stream>>>(W1, root1, WcatT, 256, 1024, 320);
  aggregate64_k<<<N_NODES, 256, 0, stream>>>(x, offs, cnt, inv, elist, Xcat);
  gemm_bt_bias_relu_k<<<8 * 80, 256, 0, stream>>>(
      (const short*)Xcat, (const short*)WcatT, b1, hA, N_NODES, 1024, 320, 8);

  // layer 2: Din=1024, K=5120, F=1024, hA -> hB
  wcat_transpose_k<<<dim3(160, 32), dim3(32, 8), 0, stream>>>(W2, root2, WcatT, 4096, 1024, 5120);
  aggregate_bf16_k<<<N_NODES * 4, 64, 0, stream>>>(hA, offs, cnt, inv, elist, Xcat);
  gemm_bt_bias_relu_k<<<8 * 80, 256, 0, stream>>>(
      (const short*)Xcat, (const short*)WcatT, b2, hB, N_NODES, 1024, 5120, 8);

  // layer 3: Din=1024, K=5120, F=712, hB -> hA (hA is dead, reuse)
  wcat_transpose_k<<<dim3(160, 23), dim3(32, 8), 0, stream>>>(W3, root3, WcatT, 4096, 712, 5120);
  aggregate_bf16_k<<<N_NODES * 4, 64, 0, stream>>>(hB, offs, cnt, inv, elist, Xcat);
  gemm_bt_bias_relu_k<<<6 * 80, 256, 0, stream>>>(
      (const short*)Xcat, (const short*)WcatT, b3, hA, N_NODES, 712, 5120, 6);

  // fused pool + head
  pool_mlp_k<<<N_GRAPHS, 256, 0, stream>>>(hA, batch, fw1, fb1, fw2, fb2, out,
                                           N_NODES, 712);
}